// Round 11
// baseline (499.113 us; speedup 1.0000x reference)
//
#include <hip/hip_runtime.h>
#include <stdint.h>

#define N_TOTAL 21840
#define NA      21888          // N_TOTAL rounded up to multiple of 64
#define W_MAX   342            // ceil(21840/64)
#define TOT_ENT 3753792u       // 64 * (342*343/2)  triangular CSR capacity
#define NMS_TH  0.3f
#define FINAL_TH 0.5f
#define NSLICE  8              // rank range-split factor

struct Inputs { const float* cls[6]; const float* reg[6]; };

// Closed-form CSR row base: row r (sorted pos) owns 342-(r>>6) slots.
__device__ __forceinline__ unsigned rowbase_u(unsigned r) {
  unsigned w = r >> 6, l = r & 63u;
  return 64u * (342u * w - (w * (w - 1u)) / 2u) + l * (342u - w);
}

// VALU-speed cross-lane u64 read (index wave-uniform) — no DS latency.
__device__ __forceinline__ unsigned long long rl_u64(unsigned long long x, int i) {
  unsigned lo = (unsigned)__builtin_amdgcn_readlane((int)(unsigned)(x & 0xffffffffull), i);
  unsigned hi = (unsigned)__builtin_amdgcn_readlane((int)(unsigned)(x >> 32), i);
  return ((unsigned long long)hi << 32) | lo;
}

// ---------------------------------------------------------------- decode ----
__global__ void decode_kernel(Inputs in,
                              float* __restrict__ dx1, float* __restrict__ dy1,
                              float* __restrict__ dx2, float* __restrict__ dy2,
                              float* __restrict__ dsc,
                              unsigned long long* __restrict__ ckey,
                              unsigned int* __restrict__ Mc,
                              unsigned int* __restrict__ rank32,
                              unsigned int* __restrict__ cnt,
                              float* __restrict__ out) {
#pragma clang fp contract(off)
  int gid = blockIdx.x * blockDim.x + threadIdx.x;
  if (gid >= N_TOTAL) return;
  rank32[gid] = 0u;
  cnt[gid] = 0u;
  if (gid < NA - N_TOTAL) cnt[N_TOTAL + gid] = 0u;
  int sc, local;
  if      (gid < 16384) { sc = 0; local = gid;         }
  else if (gid < 20480) { sc = 1; local = gid - 16384; }
  else if (gid < 21504) { sc = 2; local = gid - 20480; }
  else if (gid < 21760) { sc = 3; local = gid - 21504; }
  else if (gid < 21824) { sc = 4; local = gid - 21760; }
  else                  { sc = 5; local = gid - 21824; }
  const int Wd = 128 >> sc, stride = 4 << sc, HW = Wd * Wd;
  const int x = local & (Wd - 1), y = local >> (7 - sc);
  const float* cls = in.cls[sc];
  const float* reg = in.reg[sc];
  float c0 = cls[local], c1 = cls[HW + local];
  float m  = fmaxf(c0, c1);
  float e0 = expf(c0 - m), e1 = expf(c1 - m);
  float prob = e1 / (e0 + e1);
  float l0 = reg[local], l1 = reg[HW + local];
  float l2 = reg[2 * HW + local], l3 = reg[3 * HW + local];
  float sF  = (float)stride;
  float pcx = 0.5f * sF + (float)x * sF;
  float pcy = 0.5f * sF + (float)y * sF;
  float pwh = sF * 4.0f;
  float cx = pcx + ((l0 * 0.1f) * pwh);
  float cy = pcy + ((l1 * 0.1f) * pwh);
  float w  = pwh * expf(l2 * 0.2f);
  float h  = pwh * expf(l3 * 0.2f);
  float x1 = cx - w * 0.5f, y1 = cy - h * 0.5f;
  float x2 = x1 + w, y2 = y1 + h;
  dx1[gid] = x1; dy1[gid] = y1; dx2[gid] = x2; dy2[gid] = y2; dsc[gid] = prob;
  out[gid * 5 + 0] = 0.0f; out[gid * 5 + 1] = 0.0f; out[gid * 5 + 2] = 0.0f;
  out[gid * 5 + 3] = 0.0f; out[gid * 5 + 4] = 0.0f;
  // Only boxes with score > FINAL_TH can affect the output (suppression only
  // flows downward in score order, and only >FINAL_TH rows are exposed).
  if (prob > FINAL_TH) {
    unsigned int pos = atomicAdd(Mc, 1u);
    ckey[pos] = ((unsigned long long)__float_as_uint(prob) << 32) |
                (unsigned int)(~(unsigned int)gid);
  }
}

// ---------------------------------------------------------------- rank ------
// Count-rank with 8-way key-range split; packed atomicAdd join (measured-good).
__global__ void __launch_bounds__(256)
rank_kernel(const unsigned long long* __restrict__ ckey,
            const unsigned int* __restrict__ Mc,
            const float* __restrict__ dx1, const float* __restrict__ dy1,
            const float* __restrict__ dx2, const float* __restrict__ dy2,
            float* __restrict__ sx1, float* __restrict__ sy1,
            float* __restrict__ sx2, float* __restrict__ sy2,
            unsigned int* __restrict__ sorig,
            unsigned int* __restrict__ rank32) {
  __shared__ unsigned long long tile[256];
  const unsigned int M = *Mc;
  if (blockIdx.x * 256u >= M) return;
  const int t = (int)threadIdx.x;
  const int p = (int)blockIdx.x * 256 + t;
  unsigned long long mykey = (p < (int)M) ? ckey[p] : 0ull;
  const int S  = (int)((M + NSLICE - 1) / NSLICE);
  const int lo = (int)blockIdx.y * S;
  const int hi = min((int)M, lo + S);
  int partial = 0;
  const int nt = (hi > lo) ? ((hi - lo + 255) >> 8) : 0;
  for (int ti = 0; ti < nt; ++ti) {
    int j = lo + ti * 256 + t;
    tile[t] = (j < hi) ? ckey[j] : 0ull;
    __syncthreads();
#pragma unroll 8
    for (int q = 0; q < 256; ++q) partial += (tile[q] > mykey) ? 1 : 0;
    __syncthreads();
  }
  if (p < (int)M) {
    unsigned int pack = (unsigned int)partial | (1u << 24);
    unsigned int old  = atomicAdd(&rank32[p], pack);
    unsigned int newv = old + pack;
    if ((newv >> 24) == NSLICE) {
      int r = (int)(newv & 0xFFFFFF);
      unsigned int orig = ~(unsigned int)(mykey & 0xffffffffull);
      sx1[r] = dx1[orig]; sy1[r] = dy1[orig];
      sx2[r] = dx2[orig]; sy2[r] = dy2[orig];
      sorig[r] = orig;
    }
  }
}

// ---------------------------------------------------------------- pairs -----
// Sparse suppression structure (measured-good R7 form):
//   diag[r] = in-word bits; offd[r] = bits vs next word;
//   CSR rows rlJw/rlBits[rowbase(r)+k], k < cnt[r], for cw >= rw+2, bits != 0.
__global__ void __launch_bounds__(1024)
pairs_kernel(const float* __restrict__ sx1, const float* __restrict__ sy1,
             const float* __restrict__ sx2, const float* __restrict__ sy2,
             const unsigned int* __restrict__ Mc,
             unsigned long long* __restrict__ diag,
             unsigned long long* __restrict__ offd,
             unsigned int* __restrict__ cnt,
             unsigned short* __restrict__ rlJw,
             unsigned long long* __restrict__ rlBits) {
#pragma clang fp contract(off)
  const int M = (int)*Mc;
  const int W = (M + 63) >> 6;
  const int rw = (int)blockIdx.y;
  const int cwg = (int)blockIdx.x << 4;
  if (rw >= W || cwg >= W || cwg + 15 < rw) return;
  const int t = (int)threadIdx.x;
  const int g = t >> 6, l = t & 63;
  const int cw = cwg + g;
  __shared__ float cx1[1024], cy1[1024], cx2[1024], cy2[1024], car[1024];
  {
    int c = (cw << 6) + l;
    if (cw < W && c < M) {
      float a = sx1[c], b = sy1[c], d = sx2[c], e = sy2[c];
      cx1[t] = a; cy1[t] = b; cx2[t] = d; cy2[t] = e;
      car[t] = (d - a + 1.0f) * (e - b + 1.0f);
    }
  }
  __syncthreads();
  if (cw >= W || cw < rw) return;
  const int r = (rw << 6) + l;
  unsigned long long bits = 0ull;
  if (r < M) {
    float ax1 = sx1[r], ay1 = sy1[r], ax2 = sx2[r], ay2 = sy2[r];
    float aarea = (ax2 - ax1 + 1.0f) * (ay2 - ay1 + 1.0f);
    const int cmax = min(64, M - (cw << 6));
    const int sb = g << 6;
    for (int cc = 0; cc < cmax; ++cc) {
      int cg = (cw << 6) + cc;
      if (cg > r) {
        float xx1 = fmaxf(ax1, cx1[sb + cc]);
        float yy1 = fmaxf(ay1, cy1[sb + cc]);
        float xx2 = fminf(ax2, cx2[sb + cc]);
        float yy2 = fminf(ay2, cy2[sb + cc]);
        float ww = fmaxf(xx2 - xx1 + 1.0f, 0.0f);
        float hh = fmaxf(yy2 - yy1 + 1.0f, 0.0f);
        float inter = ww * hh;
        float iou = inter / (aarea + car[sb + cc] - inter);
        if (iou > NMS_TH) bits |= (1ull << cc);
      }
    }
  }
  if (cw == rw)            diag[r] = bits;
  else if (cw == rw + 1)   offd[r] = bits;
  else if (bits != 0ull) {
    unsigned k = atomicAdd(&cnt[r], 1u);
    unsigned b = rowbase_u((unsigned)r) + k;
    rlJw[b]   = (unsigned short)cw;
    rlBits[b] = bits;
  }
}

// ---------------------------------------------------------------- scan ------
// SINGLE-WAVE greedy scan, zero barriers (program order within the wave
// replaces all synchronization). Per step w:
//   1) apply the entry queue captured at step w-1 (targets >= w+1 — one full
//      step of load-latency slack, so the loads are done by now),
//   2) ds_read sup[w] (the only dependent latency), readlane scan,
//   3) offd carry -> sup[w+1] (LDS atomic, FIFO order),
//   4) kept lanes issue 8 independent entry loads for NEXT step's apply.
// diag/offd/cnt are unconditional 2-step-ahead double-buffers (named regs).
// Waves 1-15 park at __syncthreads and join only for the output scatter.
__global__ void __launch_bounds__(1024, 1)
scan_kernel(const unsigned long long* __restrict__ diag,
            const unsigned long long* __restrict__ offd,
            const unsigned int* __restrict__ cnt,
            const unsigned short* __restrict__ rlJw,
            const unsigned long long* __restrict__ rlBits,
            const unsigned int* __restrict__ sorig,
            const unsigned int* __restrict__ Mc,
            const float* __restrict__ dx1, const float* __restrict__ dy1,
            const float* __restrict__ dx2, const float* __restrict__ dy2,
            const float* __restrict__ dsc,
            float* __restrict__ out) {
  __shared__ unsigned long long sup[W_MAX];
  __shared__ unsigned long long kmls[W_MAX];
  const int t = (int)threadIdx.x;
  const int g = t >> 6, l = t & 63;
  const int M = (int)*Mc;
  const int W = (M + 63) >> 6;
  for (int i = t; i < W_MAX; i += 1024) { sup[i] = 0ull; kmls[i] = 0ull; }
  __syncthreads();

  if (g == 0) {
    // 2-step-ahead unconditional double buffers
    unsigned long long rb0 = (0 < W) ? diag[l] : 0ull;
    unsigned long long rb1 = (1 < W) ? diag[64 + l] : 0ull;
    unsigned long long pv0 = (1 < W) ? offd[l] : 0ull;
    unsigned long long pv1 = (2 < W) ? offd[64 + l] : 0ull;
    unsigned ct0 = (0 < W) ? cnt[l] : 0u;
    unsigned ct1 = (1 < W) ? cnt[64 + l] : 0u;
    // deferred-apply entry queue (captured at step w, applied at step w+1)
    unsigned long long qb0 = 0, qb1 = 0, qb2 = 0, qb3 = 0,
                       qb4 = 0, qb5 = 0, qb6 = 0, qb7 = 0;
    unsigned qj0 = 0, qj1 = 0, qj2 = 0, qj3 = 0,
             qj4 = 0, qj5 = 0, qj6 = 0, qj7 = 0;
    unsigned qc = 0, qrb = 0;

    for (int w = 0; w < W; ++w) {
      const int base = w << 6;
      // ---- 1) apply queued entries (targets >= w+1; loads issued last step)
      if (qc) {
        if (0u < qc) atomicOr(&sup[qj0], qb0);
        if (1u < qc) atomicOr(&sup[qj1], qb1);
        if (2u < qc) atomicOr(&sup[qj2], qb2);
        if (3u < qc) atomicOr(&sup[qj3], qb3);
        if (4u < qc) atomicOr(&sup[qj4], qb4);
        if (5u < qc) atomicOr(&sup[qj5], qb5);
        if (6u < qc) atomicOr(&sup[qj6], qb6);
        if (7u < qc) atomicOr(&sup[qj7], qb7);
        for (unsigned k = 8u; k < qc; ++k) {       // rare high-degree tail
          atomicOr(&sup[rlJw[qrb + k]], rlBits[qrb + k]);
        }
      }
      // ---- 2) scan word w
      unsigned long long supw = sup[w];        // only dependent read
      unsigned long long rowbits = rb0;
      unsigned long long pvc = pv0;
      unsigned ccur = ct0;
      rb0 = rb1; pv0 = pv1; ct0 = ct1;
      {   // issue loads for word w+2 (2 steps of slack)
        int rn = base + 128 + l;
        bool ok = (w + 2 < W);
        rb1 = ok ? diag[rn] : 0ull;
        pv1 = (w + 3 < W) ? offd[rn] : 0ull;
        ct1 = ok ? cnt[rn] : 0u;
      }
      unsigned long long nz = __ballot(rowbits != 0ull);
      const int n = min(64, M - base);
      unsigned long long wordmask = (n >= 64) ? ~0ull : ((1ull << n) - 1ull);
      unsigned long long pend = (~supw) & wordmask;
      unsigned long long kept = 0ull;
      unsigned long long act = pend & nz;
      while (act) {                     // iterations = #kept rows w/ bits (~6)
        int i = __builtin_ctzll(act);   // uniform
        unsigned long long upto = (2ull << i) - 1ull;
        kept |= pend & upto;
        unsigned long long ri = rl_u64(rowbits, i);   // VALU readlane
        pend &= ~upto;
        pend &= ~ri;
        act = pend & nz;
      }
      kept |= pend;
      if (l == 0) kmls[w] = kept;
      const bool mine = ((kept >> l) & 1ull) != 0ull;
      // ---- 3) offd carry w -> w+1 (LDS FIFO order covers step w+1's read)
      if (mine && pvc != 0ull && (w + 1 < W)) atomicOr(&sup[w + 1], pvc);
      // ---- 4) capture next queue: 8 independent loads per kept lane
      qc = mine ? ccur : 0u;
      qrb = rowbase_u((unsigned)(base + l));
      qb0 = (0u < qc) ? rlBits[qrb + 0] : 0ull;
      qb1 = (1u < qc) ? rlBits[qrb + 1] : 0ull;
      qb2 = (2u < qc) ? rlBits[qrb + 2] : 0ull;
      qb3 = (3u < qc) ? rlBits[qrb + 3] : 0ull;
      qb4 = (4u < qc) ? rlBits[qrb + 4] : 0ull;
      qb5 = (5u < qc) ? rlBits[qrb + 5] : 0ull;
      qb6 = (6u < qc) ? rlBits[qrb + 6] : 0ull;
      qb7 = (7u < qc) ? rlBits[qrb + 7] : 0ull;
      qj0 = (0u < qc) ? (unsigned)rlJw[qrb + 0] : 0u;
      qj1 = (1u < qc) ? (unsigned)rlJw[qrb + 1] : 0u;
      qj2 = (2u < qc) ? (unsigned)rlJw[qrb + 2] : 0u;
      qj3 = (3u < qc) ? (unsigned)rlJw[qrb + 3] : 0u;
      qj4 = (4u < qc) ? (unsigned)rlJw[qrb + 4] : 0u;
      qj5 = (5u < qc) ? (unsigned)rlJw[qrb + 5] : 0u;
      qj6 = (6u < qc) ? (unsigned)rlJw[qrb + 6] : 0u;
      qj7 = (7u < qc) ? (unsigned)rlJw[qrb + 7] : 0u;
    }
    // final queue needs no apply: rows in word W-1 have cnt == 0 (no cw >= W+1)
  }
  __syncthreads();

  // scatter kept rows into the (pre-zeroed) output — all 16 waves
  for (int i = t; i < (W << 6); i += 1024) {
    if ((kmls[i >> 6] >> (i & 63)) & 1ull) {
      unsigned int orig = sorig[i];
      out[(size_t)orig * 5 + 0] = dx1[orig];
      out[(size_t)orig * 5 + 1] = dy1[orig];
      out[(size_t)orig * 5 + 2] = dx2[orig];
      out[(size_t)orig * 5 + 3] = dy2[orig];
      out[(size_t)orig * 5 + 4] = dsc[orig];
    }
  }
}

// ---------------------------------------------------------------- launch ----
extern "C" void kernel_launch(void* const* d_in, const int* in_sizes, int n_in,
                              void* d_out, int out_size, void* d_ws, size_t ws_size,
                              hipStream_t stream) {
  (void)in_sizes; (void)n_in; (void)out_size; (void)ws_size;

  Inputs in;
  for (int i = 0; i < 6; ++i) {
    in.cls[i] = (const float*)d_in[2 * i];
    in.reg[i] = (const float*)d_in[2 * i + 1];
  }

  char* ws = (char*)d_ws;
  size_t o = 0;
  float* dx1 = (float*)(ws + o); o += (size_t)NA * 4;
  float* dy1 = (float*)(ws + o); o += (size_t)NA * 4;
  float* dx2 = (float*)(ws + o); o += (size_t)NA * 4;
  float* dy2 = (float*)(ws + o); o += (size_t)NA * 4;
  float* dsc = (float*)(ws + o); o += (size_t)NA * 4;
  unsigned long long* ckey = (unsigned long long*)(ws + o); o += (size_t)NA * 8;
  float* sx1 = (float*)(ws + o); o += (size_t)NA * 4;
  float* sy1 = (float*)(ws + o); o += (size_t)NA * 4;
  float* sx2 = (float*)(ws + o); o += (size_t)NA * 4;
  float* sy2 = (float*)(ws + o); o += (size_t)NA * 4;
  unsigned int* sorig = (unsigned int*)(ws + o); o += (size_t)NA * 4;
  unsigned int* rank32 = (unsigned int*)(ws + o); o += (size_t)NA * 4;
  unsigned int* cnt = (unsigned int*)(ws + o); o += (size_t)NA * 4;
  unsigned int* Mc = (unsigned int*)(ws + o); o += 64;
  o = (o + 511) & ~(size_t)511;
  unsigned long long* diag = (unsigned long long*)(ws + o); o += (size_t)NA * 8;
  unsigned long long* offd = (unsigned long long*)(ws + o); o += (size_t)NA * 8;
  unsigned long long* rlBits = (unsigned long long*)(ws + o); o += (size_t)TOT_ENT * 8;
  unsigned short* rlJw = (unsigned short*)(ws + o); o += (size_t)TOT_ENT * 2;

  const int nb = (N_TOTAL + 255) / 256;  // 86

  (void)hipMemsetAsync((void*)Mc, 0, 64, stream);
  decode_kernel<<<nb, 256, 0, stream>>>(in, dx1, dy1, dx2, dy2, dsc, ckey, Mc,
                                        rank32, cnt, (float*)d_out);
  rank_kernel<<<dim3(nb, NSLICE), 256, 0, stream>>>(ckey, Mc, dx1, dy1, dx2, dy2,
                                                    sx1, sy1, sx2, sy2, sorig,
                                                    rank32);
  pairs_kernel<<<dim3(22, W_MAX), 1024, 0, stream>>>(sx1, sy1, sx2, sy2, Mc,
                                                     diag, offd, cnt, rlJw, rlBits);
  scan_kernel<<<1, 1024, 0, stream>>>(diag, offd, cnt, rlJw, rlBits, sorig, Mc,
                                      dx1, dy1, dx2, dy2, dsc, (float*)d_out);
}